// Round 13
// baseline (316.495 us; speedup 1.0000x reference)
//
#include <hip/hip_runtime.h>
#include <hip/hip_bf16.h>

#define AS1 __attribute__((address_space(1)))
#define AS3 __attribute__((address_space(3)))

typedef __bf16 bf16x8 __attribute__((ext_vector_type(8)));
typedef float f32x4 __attribute__((ext_vector_type(4)));

#define GLOAD_LDS16(gptr, lptr) \
  __builtin_amdgcn_global_load_lds((AS1 void*)(gptr), (AS3 void*)(lptr), 16, 0, 0)

#define M_W   4096
#define K_DIM 4096
#define M_X   8192
#define NKS   (K_DIM/32)   // 128 K-steps of 32

#define BAR()      __builtin_amdgcn_s_barrier()
#define WAIT_VM6() asm volatile("s_waitcnt vmcnt(6)" ::: "memory")
#define WAIT_VM0() asm volatile("s_waitcnt vmcnt(0)" ::: "memory")

__device__ __forceinline__ unsigned short f2bf(float f) {
  unsigned int u = __float_as_uint(f);
  unsigned int r = (u + 0x7FFFu + ((u >> 16) & 1u)) >> 16;
  return (unsigned short)r;
}

// ---------------- fused prep: x fp32->bf16 (1/3 of blocks) + trellis decode (2/3) ----------------
__global__ void prep_kernel(const float* __restrict__ x,
                            const int* __restrict__ trellis,
                            const float* __restrict__ tlut,
                            unsigned short* __restrict__ xb,
                            unsigned short* __restrict__ W) {
  int b = blockIdx.x;
  int tid = threadIdx.x;
  if (b % 3 == 0) {
    int idx = (b / 3) * 256 + tid;
    const float4* p = reinterpret_cast<const float4*>(x) + (size_t)idx * 2;
    float4 u = p[0];
    float4 v = p[1];
    uint4 o;
    o.x = (unsigned)f2bf(u.x) | ((unsigned)f2bf(u.y) << 16);
    o.y = (unsigned)f2bf(u.z) | ((unsigned)f2bf(u.w) << 16);
    o.z = (unsigned)f2bf(v.x) | ((unsigned)f2bf(v.y) << 16);
    o.w = (unsigned)f2bf(v.z) | ((unsigned)f2bf(v.w) << 16);
    reinterpret_cast<uint4*>(xb)[idx] = o;
  } else {
    int db = b - b / 3 - 1;
    int idx = db * 256 + tid;
    int t = idx >> 7;
    int s = idx & 127;
    const unsigned int* tr = reinterpret_cast<const unsigned int*>(trellis) + t * 32;
    int w0  = s >> 2;
    int off = (s & 3) * 4;
    unsigned int a = tr[w0] & 0xFFFFu;
    unsigned int state;
    if (off == 0) {
      state = a;
    } else {
      unsigned int bb = tr[(w0 + 1) & 31] & 0xFFFFu;
      state = ((a << off) | (bb >> (16 - off))) & 0xFFFFu;
    }
    unsigned int code = state & 0x1FFu;
    float2 v = reinterpret_cast<const float2*>(tlut)[code];
    int i = t >> 8;
    int j = t & 255;
    int flat = s * 2;
    int r = flat >> 4;
    int c = flat & 15;
    unsigned int packed = (unsigned)f2bf(v.x) | ((unsigned)f2bf(v.y) << 16);
    size_t o = (size_t)(i * 16 + r) * K_DIM + (j * 16 + c);
    *reinterpret_cast<unsigned int*>(W + o) = packed;
  }
}

// ---------------- 256x128-tile, BK=32, 3-buffer, 2-blocks/CU GEMM ----------------
// y[8192,4096] = xb[8192,4096] * W[4096,4096]^T
// Block: 256 threads (4 waves, wr=wid>>1, wc=wid&1), per-wave output 128x64.
// LDS (72 KiB): A bufs 3 x 16 KiB at b*16384; B bufs 3 x 8 KiB at 49152 + b*8192.
// A panel 256x32 bf16 packed as [128 lrows][8 chunks of 16B]: chunk sc at lrow holds
// logical (kcp = sc ^ (lrow&7)) -> row = lrow + 128*(kcp>>2), kc = kcp&3 (B: +64*, 64 lrows).
// Per K-step s: { 32 MFMA on frags read @s-1; ds_read frags for s+1 from buf (s+1)%3;
//                stage tile min(s+3,127) -> buf s%3; vmcnt(6); barrier }.
// RAW margin 2 barriers (staged@s, gate@s+1 leaves only s+1's 6, read@s+2). WAR margin 1.

__device__ __forceinline__ void mmS(const bf16x8 (&af)[8], const bf16x8 (&bq)[4],
                                    f32x4 (&acc)[8][4]) {
  __builtin_amdgcn_s_setprio(1);
  #pragma unroll
  for (int fm = 0; fm < 8; ++fm)
    #pragma unroll
    for (int fn = 0; fn < 4; ++fn)
      acc[fm][fn] = __builtin_amdgcn_mfma_f32_16x16x32_bf16(af[fm], bq[fn], acc[fm][fn], 0, 0, 0);
  __builtin_amdgcn_s_setprio(0);
}

template<int B>
__device__ __forceinline__ void ldA(const char* lds, int aBase, bf16x8 (&af)[8]) {
  #pragma unroll
  for (int fm = 0; fm < 8; ++fm)
    af[fm] = *(const bf16x8*)(lds + B * 16384 + aBase + fm * 2048);
}

template<int B>
__device__ __forceinline__ void ldB(const char* lds, int bBase, bf16x8 (&bq)[4]) {
  #pragma unroll
  for (int fn = 0; fn < 4; ++fn)
    bq[fn] = *(const bf16x8*)(lds + 49152 + B * 8192 + bBase + fn * 2048);
}

template<int B>
__device__ __forceinline__ void stage(const unsigned short* __restrict__ xb,
                                      const unsigned short* __restrict__ W,
                                      char* lds, int kt,
                                      const size_t* aOff, const size_t* bOff, int tid16) {
  #pragma unroll
  for (int k = 0; k < 4; ++k)
    GLOAD_LDS16(xb + aOff[k] + kt * 32, lds + B * 16384 + k * 4096 + tid16);
  #pragma unroll
  for (int k = 0; k < 2; ++k)
    GLOAD_LDS16(W + bOff[k] + kt * 32, lds + 49152 + B * 8192 + k * 4096 + tid16);
}

__global__ __launch_bounds__(256, 2) void gemm_kernel(const unsigned short* __restrict__ xb,
                                                      const unsigned short* __restrict__ W,
                                                      float* __restrict__ y) {
  extern __shared__ __align__(16) char lds[];   // 73728 bytes

  // XCD-aware bijective swizzle: 1024 blocks, 8 XCDs, 128 per XCD
  int bid = blockIdx.x;
  int swz = (bid & 7) * 128 + (bid >> 3);
  int brow = (swz >> 5) * 256;   // 32 row-tiles
  int bcol = (swz & 31) * 128;   // 32 col-tiles

  int tid  = threadIdx.x;
  int lane = tid & 63;
  int wid  = tid >> 6;
  int wr = wid >> 1;     // 0..1
  int wc = wid & 1;      // 0..1
  int l15 = lane & 15;

  // ds_read addressing
  int kxorA = ((lane >> 4) + 4 * wr) ^ (lane & 7);
  int kxorB = ((lane >> 4) + 4 * wc) ^ (lane & 7);
  int aBase = l15 * 128 + kxorA * 16;
  int bBase = l15 * 128 + kxorB * 16;

  // staging addressing: thread handles chunks c = k*256 + tid
  int tid16 = tid * 16;
  int kcp = (tid & 7) ^ ((tid >> 3) & 7);
  int kcA = kcp & 3;
  size_t aOff[4], bOff[2];
  #pragma unroll
  for (int k = 0; k < 4; ++k) {
    int row = k * 32 + (tid >> 3) + 128 * (kcp >> 2);
    aOff[k] = (size_t)(brow + row) * K_DIM + kcA * 8;
  }
  #pragma unroll
  for (int k = 0; k < 2; ++k) {
    int row = k * 32 + (tid >> 3) + 64 * (kcp >> 2);
    bOff[k] = (size_t)(bcol + row) * K_DIM + kcA * 8;
  }

  f32x4 acc[8][4];
  #pragma unroll
  for (int m = 0; m < 8; ++m)
    #pragma unroll
    for (int n = 0; n < 4; ++n)
      acc[m][n] = (f32x4){0.f, 0.f, 0.f, 0.f};

  bf16x8 afA[8], afB[8];   // A fragment double-buffer (even/odd step)
  bf16x8 bqA[4], bqB[4];   // B fragment double-buffer

  // prologue: tiles 0,1,2 -> bufs 0,1,2
  stage<0>(xb, W, lds, 0, aOff, bOff, tid16);
  stage<1>(xb, W, lds, 1, aOff, bOff, tid16);
  stage<2>(xb, W, lds, 2, aOff, bOff, tid16);
  WAIT_VM0(); BAR();
  ldA<0>(lds, aBase, afA);   // tile 0 frags
  ldB<0>(lds, bBase, bqA);
  BAR();                     // separate prologue reads from s=0's restage of buf0

  #pragma unroll 1
  for (int i = 0; i < 21; ++i) {
    int s0 = 6 * i;
    int t3 = s0 + 3, t4 = s0 + 4, t5 = s0 + 5;
    int t6 = s0 + 6; if (t6 > 127) t6 = 127;
    int t7 = s0 + 7; if (t7 > 127) t7 = 127;
    int t8 = s0 + 8; if (t8 > 127) t8 = 127;

    // s0: mm t(s0) [afA,bqA]; read t(s0+1) from buf1 -> afB,bqB; stage t3 -> buf0
    mmS(afA, bqA, acc);
    ldA<1>(lds, aBase, afB); ldB<1>(lds, bBase, bqB);
    stage<0>(xb, W, lds, t3, aOff, bOff, tid16);
    WAIT_VM6(); BAR();
    // s0+1: mm [afB,bqB]; read from buf2 -> afA,bqA; stage t4 -> buf1
    mmS(afB, bqB, acc);
    ldA<2>(lds, aBase, afA); ldB<2>(lds, bBase, bqA);
    stage<1>(xb, W, lds, t4, aOff, bOff, tid16);
    WAIT_VM6(); BAR();
    // s0+2: mm [afA,bqA]; read from buf0 -> afB,bqB; stage t5 -> buf2
    mmS(afA, bqA, acc);
    ldA<0>(lds, aBase, afB); ldB<0>(lds, bBase, bqB);
    stage<2>(xb, W, lds, t5, aOff, bOff, tid16);
    WAIT_VM6(); BAR();
    // s0+3: mm [afB,bqB]; read from buf1 -> afA,bqA; stage t6 -> buf0
    mmS(afB, bqB, acc);
    ldA<1>(lds, aBase, afA); ldB<1>(lds, bBase, bqA);
    stage<0>(xb, W, lds, t6, aOff, bOff, tid16);
    WAIT_VM6(); BAR();
    // s0+4: mm [afA,bqA]; read from buf2 -> afB,bqB; stage t7 -> buf1
    mmS(afA, bqA, acc);
    ldA<2>(lds, aBase, afB); ldB<2>(lds, bBase, bqB);
    stage<1>(xb, W, lds, t7, aOff, bOff, tid16);
    WAIT_VM6(); BAR();
    // s0+5: mm [afB,bqB]; read from buf0 -> afA,bqA; stage t8 -> buf2
    mmS(afB, bqB, acc);
    ldA<0>(lds, aBase, afA); ldB<0>(lds, bBase, bqA);
    stage<2>(xb, W, lds, t8, aOff, bOff, tid16);
    WAIT_VM6(); BAR();
  }

  // tail: s=126 (tile 126, frags in afA/bqA), s=127 (tile 127 from buf1)
  mmS(afA, bqA, acc);
  ldA<1>(lds, aBase, afB); ldB<1>(lds, bBase, bqB);
  mmS(afB, bqB, acc);

  // epilogue: C/D layout col=lane&15, row=(lane>>4)*4+j
  #pragma unroll
  for (int am = 0; am < 8; ++am) {
    #pragma unroll
    for (int an = 0; an < 4; ++an) {
      int row0 = brow + wr * 128 + am * 16 + (lane >> 4) * 4;
      int col  = bcol + wc * 64 + an * 16 + l15;
      #pragma unroll
      for (int j = 0; j < 4; ++j)
        y[(size_t)(row0 + j) * M_W + col] = acc[am][an][j];
    }
  }
}

extern "C" void kernel_launch(void* const* d_in, const int* in_sizes, int n_in,
                              void* d_out, int out_size, void* d_ws, size_t ws_size,
                              hipStream_t stream) {
  const float* inp     = (const float*)d_in[0];
  const int*   trellis = (const int*)d_in[1];
  const float* tlut    = (const float*)d_in[2];
  float* y = (float*)d_out;

  unsigned short* xb = (unsigned short*)d_ws;
  unsigned short* Wd = (unsigned short*)((char*)d_ws + (size_t)M_X * K_DIM * 2);

  (void)hipFuncSetAttribute((const void*)gemm_kernel,
                            hipFuncAttributeMaxDynamicSharedMemorySize, 73728);

  prep_kernel<<<49152, 256, 0, stream>>>(inp, trellis, tlut, xb, Wd);
  gemm_kernel<<<dim3(1024), dim3(256), 73728, stream>>>(xb, Wd, y);
}